// Round 7
// baseline (388.323 us; speedup 1.0000x reference)
//
#include <hip/hip_runtime.h>

// Emission-absorption volume renderer. fp32 in/out.
// Outputs flat: [features(3NR) | depths(NR) | opac(NR) | weights(128NR)].
//
// R11: deep-read pipeline, wave-private, zero barriers.
// Evidence R0..R10: L2-level demand pinned at ~5 B/cy/CU (~3.0 TB/s) across
// five structures; reads are the pinned resource (fillBuffer writes 6.7 TB/s,
// R8's scratch writes added on top of an unchanged read stream). Every prior
// variant kept only ~2-3 load batches outstanding: register paths were
// scheduler-serialized (VGPR stuck at 24-40), the DMA path (R9) drained
// vmcnt to 0 at every __syncthreads.
// This version: 1 wave per block; ALL inputs via global_load_lds (exactly
// 5 DMA instrs per 2-ray tile: dens 1 + lens 1 + feats 3 = 5 KB);
// TRIPLE-buffered LDS; 2-tile-ahead prefetch; hand-placed counted
// s_waitcnt vmcnt(10) + sched_barrier(0) (rule #18) -> reads never drain
// to zero. Single-wave blocks: buffer safety is program order + vmcnt,
// no barrier can force a drain. 15.4 KB LDS -> 10 waves/CU, each with
// 5-15 KB reads continuously outstanding (vs ~5 KB/CU sustained before).
//
// NUMERICAL NOTE (R3): the sample-127 sentinel delta (1e10) must NOT enter
// the prefix scan (fp32 cancellation corrupts absorption near the ray end).
// It only feeds the final opacity, where exp(-~1e10) == 0.

#define BG_OPACITY_F 1e10f

typedef float floatx4 __attribute__((ext_vector_type(4)));

#define BUFW 1280     // floats per LDS tile buffer: dens 256 | lens 256 | feats 768
#define NBUF 3

// Stage one 2-ray tile (5 KB) global->LDS. 5 DMA instructions, 1 KB each
// (64 lanes x 16B contiguous). LDS dest = wave-uniform base (+ lane*16 by HW).
__device__ __forceinline__ void stage_tile(const float* __restrict__ dens,
                                           const float* __restrict__ lens,
                                           const float* __restrict__ feats,
                                           float* sbuf, long tile, int lane)
{
    typedef const __attribute__((address_space(1))) unsigned int* gp_t;
    typedef __attribute__((address_space(3))) unsigned int* lp_t;
    const float* gd = dens + tile * 256 + (long)lane * 4;
    const float* gl = lens + tile * 256 + (long)lane * 4;
    __builtin_amdgcn_global_load_lds((gp_t)gd, (lp_t)(sbuf),       16, 0, 0);
    __builtin_amdgcn_global_load_lds((gp_t)gl, (lp_t)(sbuf + 256), 16, 0, 0);
    #pragma unroll
    for (int k = 0; k < 3; ++k) {
        const float* gf = feats + tile * 768 + (long)(k * 64 + lane) * 4;
        __builtin_amdgcn_global_load_lds((gp_t)gf,
                                         (lp_t)(sbuf + 512 + k * 256), 16, 0, 0);
    }
}

__global__ __launch_bounds__(64, 2) void ea_render_kernel(
    const float* __restrict__ dens,    // (rays, 128)
    const float* __restrict__ feats,   // (rays, 128, 3)
    const float* __restrict__ lens,    // (rays, 128)
    const float* __restrict__ dirs,    // (rays, 3)
    float* __restrict__ out_feat,      // (rays, 3)
    float* __restrict__ out_depth,     // (rays)
    float* __restrict__ out_opac,      // (rays)
    float* __restrict__ out_w,         // (rays, 128)
    int n_rays)
{
    __shared__ __align__(16) float sm[NBUF * BUFW];   // 15360 B -> 10 blk/CU

    const int lane = threadIdx.x;                // block == one wave
    const int t    = lane & 31;                  // sub-lane within ray
    const int rb   = lane >> 5;                  // ray 0/1 within tile
    const long NT  = (long)(n_rays + 1) >> 1;    // 2-ray tiles
    const long G   = gridDim.x;

    long tk = blockIdx.x;
    if (tk >= NT) return;

    // ---- prologue: 2 tiles' DMAs in flight + dirs(t0) ----
    stage_tile(dens, lens, feats, sm, tk, lane);
    {
        long t1 = tk + G; if (t1 >= NT) t1 = NT - 1;
        stage_tile(dens, lens, feats, sm + BUFW, t1, lane);
    }
    long ray0 = tk * 2 + rb; if (ray0 >= n_rays) ray0 = n_rays - 1;
    float cdx = dirs[ray0 * 3 + 0];
    float cdy = dirs[ray0 * 3 + 1];
    float cdz = dirs[ray0 * 3 + 2];

    int bi = 0;                                   // buffer of current tile
    for (; tk < NT; tk += G) {
        // ---- stage tile k+2 into buffer (bi+2)%3 (read 2 iters from now) --
        long t2 = tk + 2 * G; if (t2 >= NT) t2 = NT - 1;
        int  b2 = bi + 2; if (b2 >= NBUF) b2 -= NBUF;
        stage_tile(dens, lens, feats, sm + b2 * BUFW, t2, lane);

        // Counted wait: allow the 10 youngest VMEM ops (>= DMA(k+2) and the
        // tail of last iter's stores) to stay in flight; everything older --
        // including DMA(k), whose buffer we read below -- must have landed.
        asm volatile("s_waitcnt vmcnt(10)" ::: "memory");
        __builtin_amdgcn_sched_barrier(0);        // rule #18: pin code below

        // prefetch next tile's dirs (tiny; 1 iteration of cover)
        long tn = tk + G; if (tn >= NT) tn = tk;
        long rayn = tn * 2 + rb; if (rayn >= n_rays) rayn = n_rays - 1;
        const float ndx = dirs[rayn * 3 + 0];
        const float ndy = dirs[rayn * 3 + 1];
        const float ndz = dirs[rayn * 3 + 2];

        // ---- compute tile tk from LDS buffer bi ----
        const float* sc = sm + bi * BUFW;
        long ray = tk * 2 + rb; if (ray >= n_rays) ray = n_rays - 1;
        const long base = ray * 128;
        const int  n0   = t * 4;                  // first of 4 samples owned

        const float4 dq = *(const float4*)(sc + lane * 4);          // dens
        const float4 lq = *(const float4*)(sc + 256 + lane * 4);    // lens
        const float* fw = sc + 512 + rb * 384 + t * 12;             // feats
        const float4 q0 = *(const float4*)(fw);
        const float4 q1 = *(const float4*)(fw + 4);
        const float4 q2 = *(const float4*)(fw + 8);

        const float dn = sqrtf(cdx * cdx + cdy * cdy + cdz * cdz);

        // next lane's first length (delta of our last sample); at t==31 the
        // value crosses the ray boundary - unused there (sentinel).
        const float lnext = __shfl_down(lq.x, 1, 64);

        const float w0 = (lq.y - lq.x) * dn * fmaxf(dq.x, 0.0f);
        const float w1 = (lq.z - lq.y) * dn * fmaxf(dq.y, 0.0f);
        const float w2 = (lq.w - lq.z) * dn * fmaxf(dq.z, 0.0f);
        const float delta3 = (t == 31) ? BG_OPACITY_F : (lnext - lq.w);
        const float w3 = delta3 * dn * fmaxf(dq.w, 0.0f);
        const float w3s = (t == 31) ? 0.0f : w3;   // sentinel excluded
        const float s = w0 + w1 + w2 + w3s;

        // 32-lane inclusive scan of per-lane sums (5 dependent steps)
        float inc = s;
        #pragma unroll
        for (int off = 1; off < 32; off <<= 1) {
            const float u = __shfl_up(inc, off, 64);
            if (t >= off) inc += u;                // t-mask keeps rays apart
        }
        const float excl = inc - s;                // sum over all n < n0

        // weights: wgt[i] = (1 - exp(-w[i])) * exp(-prefix_excl[i])
        float a = __expf(-excl);
        const float e0 = __expf(-w0), e1 = __expf(-w1);
        const float e2 = __expf(-w2), e3 = __expf(-w3);  // t31: exp(-1e10)=0
        const float g0 = (1.0f - e0) * a;
        const float a1 = a * e0;
        const float g1 = (1.0f - e1) * a1;
        const float a2 = a1 * e1;
        const float g2 = (1.0f - e2) * a2;
        const float a3 = a2 * e2;
        const float g3 = (1.0f - e3) * a3;

        // weights out (streamed, never re-read -> nontemporal)
        const floatx4 wv = {g0, g1, g2, g3};
        __builtin_nontemporal_store(wv, (floatx4*)(out_w + base + n0));

        if (t == 31) {
            // inc == total real weighted; re-add sentinel for opacity.
            out_opac[ray] = 1.0f - __expf(-(inc + w3));
        }

        float pd = g0 * lq.x + g1 * lq.y + g2 * lq.z + g3 * lq.w;
        // sample->color words: s0:(q0.x,y,z) s1:(q0.w,q1.x,y)
        //                      s2:(q1.z,w,q2.x) s3:(q2.y,z,w)
        float fr = g0 * q0.x + g1 * q0.w + g2 * q1.z + g3 * q2.y;
        float fg = g0 * q0.y + g1 * q1.x + g2 * q1.w + g3 * q2.z;
        float fb = g0 * q0.z + g1 * q1.y + g2 * q2.x + g3 * q2.w;

        // 32-lane butterfly reductions (xor stays within ray group)
        #pragma unroll
        for (int off = 16; off; off >>= 1) {
            pd += __shfl_xor(pd, off, 64);
            fr += __shfl_xor(fr, off, 64);
            fg += __shfl_xor(fg, off, 64);
            fb += __shfl_xor(fb, off, 64);
        }

        if (t == 0) {
            // features += (1 - opac) * BG_COLOR with BG_COLOR==0 -> no-op
            out_feat[ray * 3 + 0] = fr;
            out_feat[ray * 3 + 1] = fg;
            out_feat[ray * 3 + 2] = fb;
            out_depth[ray] = pd;
        }

        // rotate (named scalars / small int only - SROA-safe)
        cdx = ndx; cdy = ndy; cdz = ndz;
        bi += 1; if (bi >= NBUF) bi = 0;
    }
}

extern "C" void kernel_launch(void* const* d_in, const int* in_sizes, int n_in,
                              void* d_out, int out_size, void* d_ws, size_t ws_size,
                              hipStream_t stream) {
    // Input order verified (R4 decode): dens(0), feats(1), lens(2), dirs(3).
    const float* dens  = (const float*)d_in[0];  // (B,R,N,1)
    const float* feats = (const float*)d_in[1];  // (B,R,N,3)
    const float* lens  = (const float*)d_in[2];  // (B,R,N)
    const float* dirs  = (const float*)d_in[3];  // (B,R,3)

    const int n_rays = in_sizes[3] / 3;          // B*R = 131072

    float* out = (float*)d_out;
    float* out_feat  = out;                       // (rays, 3)
    float* out_depth = out + (long)n_rays * 3;    // (rays, 1)
    float* out_opac  = out + (long)n_rays * 4;    // (rays, 1)
    float* out_w     = out + (long)n_rays * 5;    // (rays, 128)

    const long n_tiles = (long)(n_rays + 1) / 2;  // 65536
    // 10 blocks/CU (LDS-limited) x 256 CUs = 2560 persistent single-wave
    // blocks; grid-stride the rest.
    const int blocks = (int)(n_tiles < 2560 ? n_tiles : 2560);
    ea_render_kernel<<<blocks, 64, 0, stream>>>(
        dens, feats, lens, dirs, out_feat, out_depth, out_opac, out_w, n_rays);
}

// Round 8
// 358.931 us; speedup vs baseline: 1.0819x; 1.0819x over previous
//
#include <hip/hip_runtime.h>

// Emission-absorption volume renderer. fp32 in/out (outputs flat:
// [features(3NR) | depths(NR) | opac(NR) | weights(128NR)], NR=131072).
// One 64-lane wave per ray; lane l owns samples n=2l and n=2l+1.
//
// R12 = R0 (best measured: 120-125us/dispatch) + cache-placement hints.
// Evidence R0..R11: read delivery pinned at ~5 B/cy/CU (~3.2 TB/s chip)
// across six structures incl. a verified deep-DMA pipeline (R11: 10KB/wave
// outstanding, same BW) -> per-CU line-fill concurrency cap shared by all
// waves; structure can't beat it, only fill LATENCY mix can. m13's copy
// "6.3 TB/s" = ~3.15 read + ~3.15 write: read half == our cap.
// Lever here: nontemporal LOADS on feats (201MB, 60% of reads: no-allocate,
// pure HBM stream) so dens+lens (134MB) stay L3-resident across dispatches
// and their fills turn over at L3 latency; nontemporal STORE on weights so
// the 67MB output never evicts inputs. FETCH rising to ~200-215MB is the
// EXPECTED signature (feats all-HBM, dens/lens ~free), not a regression.
//
// KEY NUMERICAL FIX (R3, keep forever): the lane-63 sentinel delta (1e10)
// must NOT enter the prefix scan - at 2e10 the fp32 ulp is 2048, so
// excl = inc - s cancels catastrophically and absorption_shifted[126..127]
// comes out ~1 instead of exp(-S_prev). The sentinel only ever feeds the
// final opacity, where exp(-2e10) == 0.

#define BG_OPACITY_F 1e10f

typedef float floatx2 __attribute__((ext_vector_type(2)));

__global__ __launch_bounds__(256) void ea_render_kernel(
    const float* __restrict__ dens,    // (rays, 128)
    const float* __restrict__ feats,   // (rays, 128, 3)
    const float* __restrict__ lens,    // (rays, 128)
    const float* __restrict__ dirs,    // (rays, 3)
    float* __restrict__ out_feat,      // (rays, 3)
    float* __restrict__ out_depth,     // (rays)
    float* __restrict__ out_opac,      // (rays)
    float* __restrict__ out_w,         // (rays, 128)
    int n_rays)
{
    const int wave = threadIdx.x >> 6;               // 0..3
    const int lane = threadIdx.x & 63;
    const long ray = (long)blockIdx.x * 4 + wave;
    if (ray >= n_rays) return;

    const long base = ray * 128;
    const int n0 = lane * 2;

    // ---- coalesced loads (8 B / lane); dens/lens ALLOCATE (L3-resident
    //      across dispatches once feats stops thrashing the IC) ----
    const float2 d2 = *(const float2*)(dens + base + n0);   // densities
    const float2 l2 = *(const float2*)(lens + base + n0);   // lengths

    // feats: 60% of read bytes, zero reuse -> nontemporal (no-allocate)
    const float* fp = feats + base * 3 + (long)n0 * 3;      // 24B/lane, 8B-aligned
    const floatx2 f01 = __builtin_nontemporal_load((const floatx2*)(fp));
    const floatx2 f23 = __builtin_nontemporal_load((const floatx2*)(fp + 2));
    const floatx2 f45 = __builtin_nontemporal_load((const floatx2*)(fp + 4));

    // ray direction norm (12 B broadcast from cache)
    const float* dp = dirs + ray * 3;
    const float dx = dp[0], dy = dp[1], dz = dp[2];
    const float dn = sqrtf(dx * dx + dy * dy + dz * dz);

    // ---- deltas ----
    // delta[n] = len[n+1]-len[n], n<127 ; delta[127] = BG_OPACITY
    const float lnext = __shfl_down(l2.x, 1, 64);   // lane l <- lane l+1's len[2l+2]
    const float delta0 = l2.y - l2.x;
    const float delta1 = (lane == 63) ? BG_OPACITY_F : (lnext - l2.y);

    const float w0 = delta0 * dn * fmaxf(d2.x, 0.0f);
    const float w1 = delta1 * dn * fmaxf(d2.y, 0.0f);

    // ---- wave-wide inclusive scan of per-lane pair sums ----
    // Sentinel excluded: scanned values stay O(10), no cancellation.
    const float w1s = (lane == 63) ? 0.0f : w1;
    const float s = w0 + w1s;
    float inc = s;
    #pragma unroll
    for (int off = 1; off < 64; off <<= 1) {
        const float t = __shfl_up(inc, off, 64);
        if (lane >= off) inc += t;
    }
    const float excl = inc - s;        // sum of weighted over all n < 2l

    // ---- weights ----
    const float e0 = __expf(-w0);
    const float e1 = __expf(-w1);      // lane 63: exp(-~2e10) = 0
    const float a0 = __expf(-excl);    // absorption_shifted at n0
    const float a1 = a0 * e0;          // absorption_shifted at n0+1
    const float wgt0 = (1.0f - e0) * a0;
    const float wgt1 = (1.0f - e1) * a1;

    // ---- opacity: re-add the sentinel term (reference cumsum[127]) ----
    const float total_real = __shfl(inc, 63, 64);   // sum of real weighted
    const float w1_last    = __shfl(w1, 63, 64);    // sentinel weighted term
    const float opac = 1.0f - __expf(-(total_real + w1_last));

    // ---- per-lane partials ----
    float pd = wgt0 * l2.x + wgt1 * l2.y;

    // sample n0:   (f01.x, f01.y, f23.x)   sample n0+1: (f23.y, f45.x, f45.y)
    float fr = wgt0 * f01.x + wgt1 * f23.y;
    float fg = wgt0 * f01.y + wgt1 * f45.x;
    float fb = wgt0 * f23.x + wgt1 * f45.y;

    // ---- wave butterfly reductions (depth + 3 feature channels) ----
    #pragma unroll
    for (int off = 32; off; off >>= 1) {
        pd += __shfl_xor(pd, off, 64);
        fr += __shfl_xor(fr, off, 64);
        fg += __shfl_xor(fg, off, 64);
        fb += __shfl_xor(fb, off, 64);
    }

    // ---- stores ----
    // weights: streamed, never re-read -> nontemporal (don't evict inputs)
    const floatx2 wv = {wgt0, wgt1};
    __builtin_nontemporal_store(wv, (floatx2*)(out_w + base + n0));

    if (lane == 0) {
        // features += (1 - opac) * BG_COLOR with BG_COLOR == 0 -> no-op
        out_feat[ray * 3 + 0] = fr;
        out_feat[ray * 3 + 1] = fg;
        out_feat[ray * 3 + 2] = fb;
        out_depth[ray] = pd;
        out_opac[ray] = opac;
    }
}

extern "C" void kernel_launch(void* const* d_in, const int* in_sizes, int n_in,
                              void* d_out, int out_size, void* d_ws, size_t ws_size,
                              hipStream_t stream) {
    // Input order verified (R4 decode): dens(0), feats(1), lens(2), dirs(3).
    const float* dens  = (const float*)d_in[0];  // (B,R,N,1)
    const float* feats = (const float*)d_in[1];  // (B,R,N,3)
    const float* lens  = (const float*)d_in[2];  // (B,R,N)
    const float* dirs  = (const float*)d_in[3];  // (B,R,3)

    const int n_rays = in_sizes[3] / 3;          // B*R = 131072

    float* out = (float*)d_out;
    float* out_feat  = out;                       // (rays, 3)
    float* out_depth = out + (long)n_rays * 3;    // (rays, 1)
    float* out_opac  = out + (long)n_rays * 4;    // (rays, 1)
    float* out_w     = out + (long)n_rays * 5;    // (rays, 128)

    const int blocks = (n_rays + 3) / 4;          // 4 rays (waves) per block
    ea_render_kernel<<<blocks, 256, 0, stream>>>(
        dens, feats, lens, dirs, out_feat, out_depth, out_opac, out_w, n_rays);
}